// Round 7
// baseline (474.576 us; speedup 1.0000x reference)
//
#include <hip/hip_runtime.h>
#include <math.h>

// Problem constants (match reference)
#define MB 8      // batch
#define MM 384    // checks
#define NN 1536   // variables
#define LL 20     // layers
#define RW 8      // row weight of H
#define HE 4      // edges per thread (half row)
#define NE (MM*RW)  // 3072 edges
#define NT 768    // bp block size (2 threads per check row)

// ---------------------------------------------------------------------------
// DIAGNOSTIC: spin until clock64() (s_memtime, core-clocked) advances 480k
// ticks. The dispatch's dur_us in rocprof = 480e3 / f_core:
//   200 us -> 2.4 GHz ; 1 ms -> 480 MHz ; 2.8 ms -> ~170 MHz.
// Writes only to d_ws scratch (never touches d_out).
// ---------------------------------------------------------------------------
__global__ void spin_kernel(unsigned long long* ws_sink) {
    if (threadIdx.x == 0) {
        unsigned long long t0 = clock64();
        unsigned long long it = 0;
        while (clock64() - t0 < 480000ULL) ++it;
        ws_sink[0] = it;   // side effect so the loop can't be elided
    }
}

// ---------------------------------------------------------------------------
// Fused setup: one block (256 thr = 4 waves) per check row.
//  4-wave ballot scan of H row m -> RW column indices (order-preserving),
//  then gather all per-layer edge weights into contiguous ws arrays.
//  Block 0 zeroes the output scalar.
// ---------------------------------------------------------------------------
__global__ __launch_bounds__(256) void setup_kernel(
    const float* __restrict__ H,
    const float* __restrict__ llrs,
    const float* __restrict__ w_llr,
    const float* __restrict__ w_de,
    const float* __restrict__ marg_de,
    int*   __restrict__ col_idx,
    float* __restrict__ marg_e,
    float* __restrict__ base_e,
    float* __restrict__ wde_e,
    float* __restrict__ out) {
    const int m = blockIdx.x;
    const int t = threadIdx.x;
    const int w = t >> 6, lane = t & 63;
    __shared__ int s_qcol[4][RW];
    __shared__ int s_qcnt[4];
    __shared__ int s_col[RW];

    const float* row = H + (size_t)m * NN;
    int count = 0;
    for (int c0 = w * 384; c0 < (w + 1) * 384; c0 += 64) {
        float v = row[c0 + lane];
        unsigned long long mask = __ballot(v != 0.0f);
        if (v != 0.0f) {
            int pos = count + (int)__popcll(mask & ((1ull << lane) - 1ull));
            if (pos < RW) s_qcol[w][pos] = c0 + lane;
        }
        count += (int)__popcll(mask);
    }
    if (lane == 0) s_qcnt[w] = (count < RW) ? count : RW;
    __syncthreads();
    if (t == 0) {
        int off = 0;
        for (int q = 0; q < 4; ++q)
            for (int i = 0; i < s_qcnt[q]; ++i) {
                if (off < RW) s_col[off] = s_qcol[q][i];
                ++off;
            }
    }
    __syncthreads();

    if (t < RW) {
        int c = s_col[t];
        col_idx[m * RW + t] = c;
        marg_e[m * RW + t]  = marg_de[m * NN + c];
    }
    if (m == 0 && t == 0) out[0] = 0.0f;

    for (int idx = t; idx < LL * RW; idx += 256) {
        int l = idx >> 3;
        int k = idx & 7;
        int c = s_col[k];
        base_e[l * NE + m * RW + k] = llrs[c] * w_llr[l * NN + c];
        wde_e [l * NE + m * RW + k] = w_de[(size_t)l * MM * NN + (size_t)m * NN + c];
    }
}

// ---------------------------------------------------------------------------
// Main BP kernel (R5 structure, micro-trimmed): 8 blocks, 768 threads =
// 2 per check row. ONE barrier per layer; 3-buffer S rotation; belief
// ping-pong with deferred loss; native ds_add_f32; float4 weight prefetch.
// Trims: exclusive product = ptot * rcp(d_k)  (== reference's p/d),
//        clamp via med3-style fmin/fmax kept, guard via cndmask.
// ---------------------------------------------------------------------------
__global__ __launch_bounds__(NT) void bp_kernel(
    const float* __restrict__ synd,       // (B,M,1)
    const float* __restrict__ errors,     // (B,N)
    const float* __restrict__ llrs,       // (N)
    const float* __restrict__ marg_llr,   // (N)
    const float* __restrict__ res_w,      // (L)
    const float* __restrict__ rhos,       // (L)
    const int*   __restrict__ col_idx,    // (E)
    const float* __restrict__ marg_e_g,   // (E)
    const float* __restrict__ base_e_g,   // (L,E)
    const float* __restrict__ wde_e_g,    // (L,E)
    float* __restrict__ out) {

    __shared__ float s_S[3][NN];
    __shared__ float s_bel[2][NN];
    __shared__ float s_rw[LL];
    __shared__ float s_rho[LL];
    __shared__ float s_red[12];

    const int b = blockIdx.x;
    const int t = threadIdx.x;
    const int m = t >> 1;        // check row; edges owned: t*HE + k

    int col[HE];
    {
        const int4 ci = ((const int4*)col_idx)[t];
        col[0] = ci.x; col[1] = ci.y; col[2] = ci.z; col[3] = ci.w;
    }
    float msg[HE] = {0.0f, 0.0f, 0.0f, 0.0f};
    float marg[HE];
    {
        const float4 mg = ((const float4*)marg_e_g)[t];
        marg[0] = mg.x; marg[1] = mg.y; marg[2] = mg.z; marg[3] = mg.w;
    }
    const float sgn = 1.0f - 2.0f * synd[b * MM + m];

    float bias[2], omeg[2];
    #pragma unroll
    for (int i = 0; i < 2; ++i) {
        int n = t + i * NT;
        bias[i] = llrs[n] * marg_llr[n];
        omeg[i] = 1.0f - errors[b * NN + n];
        s_S[0][n] = 0.0f; s_S[1][n] = 0.0f; s_S[2][n] = 0.0f;
        s_bel[0][n] = bias[i]; s_bel[1][n] = bias[i];
    }
    if (t < LL) { s_rw[t] = res_w[t]; s_rho[t] = rhos[t]; }

    float bc[HE], wS[HE], bn[HE], wn2[HE];
    {
        const float4 bp4 = ((const float4*)(base_e_g))[t];
        bc[0] = bp4.x; bc[1] = bp4.y; bc[2] = bp4.z; bc[3] = bp4.w;
        const float4 wp4 = ((const float4*)(wde_e_g + 1 * NE))[t];
        wS[0] = wp4.x; wS[1] = wp4.y; wS[2] = wp4.z; wS[3] = wp4.w;
    }

    float loss = 0.0f;
    __syncthreads();

    for (int l = 0; l < LL; ++l) {
        {
            int lb = (l + 1 < LL) ? (l + 1) : (LL - 1);
            int lw = (l + 2 < LL) ? (l + 2) : (LL - 1);
            const float4 bp4 = ((const float4*)(base_e_g + lb * NE))[t];
            bn[0]  = bp4.x; bn[1]  = bp4.y; bn[2]  = bp4.z; bn[3]  = bp4.w;
            const float4 wp4 = ((const float4*)(wde_e_g + lw * NE))[t];
            wn2[0] = wp4.x; wn2[1] = wp4.y; wn2[2] = wp4.z; wn2[3] = wp4.w;
        }

        if (l > 0) {
            const float rr = s_rho[l - 1];
            const int   pb = (l - 1) & 1;
            float acc = 0.0f;
            #pragma unroll
            for (int i = 0; i < 2; ++i) {
                int n = t + i * NT;
                float be = s_bel[pb][n];
                float sp = fmaxf(be, 0.0f) + __logf(1.0f + __expf(-fabsf(be)));
                acc += sp - omeg[i] * be;
                s_bel[pb][n] = bias[i];
            }
            loss += rr * acc;
        }

        {
            const int sb = (l + 2) % 3;
            s_S[sb][t] = 0.0f;
            s_S[sb][t + NT] = 0.0f;
        }

        const float rw_ = s_rw[l];
        const int cs = l % 3, ns = (l + 1) % 3, bb = l & 1;

        float d[HE];
        #pragma unroll
        for (int k = 0; k < HE; ++k) {
            float te = bc[k] + s_S[cs][col[k]] - msg[k];
            float e  = __expf(te);
            float dd = 1.0f - 2.0f * __builtin_amdgcn_rcpf(e + 1.0f);
            dd = fminf(fmaxf(dd, -1.0f), 1.0f);
            if (dd == 0.0f) dd = 1.0f;        // jnp.where(d==0,1,d)
            d[k] = dd;
        }
        float p01 = d[0] * d[1], p23 = d[2] * d[3];
        float p4  = p01 * p23;
        float pot = __shfl_xor(p4, 1, 64);    // partner half's product
        float ptot = p4 * pot;                // full row product (reference's p)

        #pragma unroll
        for (int k = 0; k < HE; ++k) {
            float x  = ptot * __builtin_amdgcn_rcpf(d[k]);   // reference's p/d
            float r  = (1.0f + x) * __builtin_amdgcn_rcpf(1.0f - x);
            float nm = sgn * __logf(r) + rw_ * msg[k];       // 2*atanh*sgn + res*msg
            msg[k] = nm;
            unsafeAtomicAdd(&s_S[ns][col[k]], nm * wS[k]);   // ds_add_f32
            unsafeAtomicAdd(&s_bel[bb][col[k]], nm * marg[k]);
        }

        #pragma unroll
        for (int k = 0; k < HE; ++k) { bc[k] = bn[k]; wS[k] = wn2[k]; }

        __syncthreads();
    }

    {
        const float rr = s_rho[LL - 1];
        const int   pb = (LL - 1) & 1;
        float acc = 0.0f;
        #pragma unroll
        for (int i = 0; i < 2; ++i) {
            int n = t + i * NT;
            float be = s_bel[pb][n];
            float sp = fmaxf(be, 0.0f) + __logf(1.0f + __expf(-fabsf(be)));
            acc += sp - omeg[i] * be;
        }
        loss += rr * acc;
    }

    #pragma unroll
    for (int off = 32; off > 0; off >>= 1)
        loss += __shfl_down(loss, off, 64);
    int wave = t >> 6, lane = t & 63;
    if (lane == 0) s_red[wave] = loss;
    __syncthreads();
    if (t == 0) {
        float tot = 0.0f;
        #pragma unroll
        for (int w = 0; w < 12; ++w) tot += s_red[w];
        atomicAdd(out, tot * (1.0f / (float)MB));
    }
}

// ---------------------------------------------------------------------------
extern "C" void kernel_launch(void* const* d_in, const int* in_sizes, int n_in,
                              void* d_out, int out_size, void* d_ws, size_t ws_size,
                              hipStream_t stream) {
    const float* synd     = (const float*)d_in[0];
    const float* errors   = (const float*)d_in[1];
    const float* H        = (const float*)d_in[2];
    const float* llrs     = (const float*)d_in[3];
    const float* w_de     = (const float*)d_in[4];
    const float* w_llr    = (const float*)d_in[5];
    const float* marg_de  = (const float*)d_in[6];
    const float* marg_llr = (const float*)d_in[7];
    const float* res_w    = (const float*)d_in[8];
    const float* rhos     = (const float*)d_in[9];
    float* out = (float*)d_out;

    // Workspace layout (4-byte elements, 16B-aligned partitions)
    int*   col_idx = (int*)d_ws;            // NE ints
    float* marg_e  = (float*)d_ws + NE;     // NE floats
    float* base_e  = marg_e + NE;           // L*NE floats
    float* wde_e   = base_e + LL * NE;      // L*NE floats
    unsigned long long* spin_sink =
        (unsigned long long*)((char*)d_ws + ws_size - 16);

    setup_kernel<<<MM, 256, 0, stream>>>(H, llrs, w_llr, w_de, marg_de,
                                         col_idx, marg_e, base_e, wde_e, out);
    bp_kernel<<<MB, NT, 0, stream>>>(synd, errors, llrs, marg_llr, res_w, rhos,
                                     col_idx, marg_e, base_e, wde_e, out);
    // Diagnostic (after bp so it doesn't delay it): dur_us = 480e3 / f_core
    spin_kernel<<<1, 64, 0, stream>>>(spin_sink);
}

// Round 8
// 443.133 us; speedup vs baseline: 1.0710x; 1.0710x over previous
//
#include <hip/hip_runtime.h>
#include <math.h>

// Problem constants (match reference)
#define MB 8      // batch
#define MM 384    // checks
#define NN 1536   // variables
#define LL 20     // layers
#define RW 8      // row weight of H
#define HE 4      // edges per thread (half row)
#define NE (MM*RW)  // 3072 edges
#define NT 768    // bp block size (2 threads per check row)

#define REP_CAP 2400000ULL   // 1 ms max per reporter

// ---------------------------------------------------------------------------
// Phase reporters: spin for diag[i] core ticks -> rocprof dur_us = cycles/2400.
// ---------------------------------------------------------------------------
__global__ void rep_p0(const unsigned long long* diag, unsigned long long* sink) {
    if (threadIdx.x == 0) {
        unsigned long long tgt = diag[0]; if (tgt > REP_CAP) tgt = REP_CAP;
        unsigned long long t0 = clock64(), it = 0;
        while (clock64() - t0 < tgt) ++it;
        sink[1] = it;
    }
}
__global__ void rep_p1(const unsigned long long* diag, unsigned long long* sink) {
    if (threadIdx.x == 0) {
        unsigned long long tgt = diag[1]; if (tgt > REP_CAP) tgt = REP_CAP;
        unsigned long long t0 = clock64(), it = 0;
        while (clock64() - t0 < tgt) ++it;
        sink[2] = it;
    }
}
__global__ void rep_p2(const unsigned long long* diag, unsigned long long* sink) {
    if (threadIdx.x == 0) {
        unsigned long long tgt = diag[2]; if (tgt > REP_CAP) tgt = REP_CAP;
        unsigned long long t0 = clock64(), it = 0;
        while (clock64() - t0 < tgt) ++it;
        sink[3] = it;
    }
}
__global__ void rep_p3(const unsigned long long* diag, unsigned long long* sink) {
    if (threadIdx.x == 0) {
        unsigned long long tgt = diag[3]; if (tgt > REP_CAP) tgt = REP_CAP;
        unsigned long long t0 = clock64(), it = 0;
        while (clock64() - t0 < tgt) ++it;
        sink[4] = it;
    }
}

// ---------------------------------------------------------------------------
// Fused setup: one block (256 thr = 4 waves) per check row (unchanged).
// ---------------------------------------------------------------------------
__global__ __launch_bounds__(256) void setup_kernel(
    const float* __restrict__ H,
    const float* __restrict__ llrs,
    const float* __restrict__ w_llr,
    const float* __restrict__ w_de,
    const float* __restrict__ marg_de,
    int*   __restrict__ col_idx,
    float* __restrict__ marg_e,
    float* __restrict__ base_e,
    float* __restrict__ wde_e,
    float* __restrict__ out) {
    const int m = blockIdx.x;
    const int t = threadIdx.x;
    const int w = t >> 6, lane = t & 63;
    __shared__ int s_qcol[4][RW];
    __shared__ int s_qcnt[4];
    __shared__ int s_col[RW];

    const float* row = H + (size_t)m * NN;
    int count = 0;
    for (int c0 = w * 384; c0 < (w + 1) * 384; c0 += 64) {
        float v = row[c0 + lane];
        unsigned long long mask = __ballot(v != 0.0f);
        if (v != 0.0f) {
            int pos = count + (int)__popcll(mask & ((1ull << lane) - 1ull));
            if (pos < RW) s_qcol[w][pos] = c0 + lane;
        }
        count += (int)__popcll(mask);
    }
    if (lane == 0) s_qcnt[w] = (count < RW) ? count : RW;
    __syncthreads();
    if (t == 0) {
        int off = 0;
        for (int q = 0; q < 4; ++q)
            for (int i = 0; i < s_qcnt[q]; ++i) {
                if (off < RW) s_col[off] = s_qcol[q][i];
                ++off;
            }
    }
    __syncthreads();

    if (t < RW) {
        int c = s_col[t];
        col_idx[m * RW + t] = c;
        marg_e[m * RW + t]  = marg_de[m * NN + c];
    }
    if (m == 0 && t == 0) out[0] = 0.0f;

    for (int idx = t; idx < LL * RW; idx += 256) {
        int l = idx >> 3;
        int k = idx & 7;
        int c = s_col[k];
        base_e[l * NE + m * RW + k] = llrs[c] * w_llr[l * NN + c];
        wde_e [l * NE + m * RW + k] = w_de[(size_t)l * MM * NN + (size_t)m * NN + c];
    }
}

// ---------------------------------------------------------------------------
// Main BP kernel — R7 structure + clock64 phase timers.
//  P0: prefetch issue + deferred loss + resets
//  P1: S-gather + check compute + shfl + per-k math + scatter ISSUE
//  P2: s_waitcnt vmcnt(0) lgkmcnt(0)  (atomic + weight-load completion)
//  P3: __syncthreads residual (inter-wave skew)
// ---------------------------------------------------------------------------
__global__ __launch_bounds__(NT) void bp_kernel(
    const float* __restrict__ synd,
    const float* __restrict__ errors,
    const float* __restrict__ llrs,
    const float* __restrict__ marg_llr,
    const float* __restrict__ res_w,
    const float* __restrict__ rhos,
    const int*   __restrict__ col_idx,
    const float* __restrict__ marg_e_g,
    const float* __restrict__ base_e_g,
    const float* __restrict__ wde_e_g,
    float* __restrict__ out,
    unsigned long long* __restrict__ diag) {

    __shared__ float s_S[3][NN];
    __shared__ float s_bel[2][NN];
    __shared__ float s_rw[LL];
    __shared__ float s_rho[LL];
    __shared__ float s_red[12];

    const int b = blockIdx.x;
    const int t = threadIdx.x;
    const int m = t >> 1;

    int col[HE];
    {
        const int4 ci = ((const int4*)col_idx)[t];
        col[0] = ci.x; col[1] = ci.y; col[2] = ci.z; col[3] = ci.w;
    }
    float msg[HE] = {0.0f, 0.0f, 0.0f, 0.0f};
    float marg[HE];
    {
        const float4 mg = ((const float4*)marg_e_g)[t];
        marg[0] = mg.x; marg[1] = mg.y; marg[2] = mg.z; marg[3] = mg.w;
    }
    const float sgn = 1.0f - 2.0f * synd[b * MM + m];

    float bias[2], omeg[2];
    #pragma unroll
    for (int i = 0; i < 2; ++i) {
        int n = t + i * NT;
        bias[i] = llrs[n] * marg_llr[n];
        omeg[i] = 1.0f - errors[b * NN + n];
        s_S[0][n] = 0.0f; s_S[1][n] = 0.0f; s_S[2][n] = 0.0f;
        s_bel[0][n] = bias[i]; s_bel[1][n] = bias[i];
    }
    if (t < LL) { s_rw[t] = res_w[t]; s_rho[t] = rhos[t]; }

    float bc[HE], wS[HE], bn[HE], wn2[HE];
    {
        const float4 bp4 = ((const float4*)(base_e_g))[t];
        bc[0] = bp4.x; bc[1] = bp4.y; bc[2] = bp4.z; bc[3] = bp4.w;
        const float4 wp4 = ((const float4*)(wde_e_g + 1 * NE))[t];
        wS[0] = wp4.x; wS[1] = wp4.y; wS[2] = wp4.z; wS[3] = wp4.w;
    }

    float loss = 0.0f;
    unsigned long long p0 = 0, p1 = 0, p2 = 0, p3 = 0;
    __syncthreads();

    for (int l = 0; l < LL; ++l) {
        unsigned long long tA = clock64();

        {
            int lb = (l + 1 < LL) ? (l + 1) : (LL - 1);
            int lw = (l + 2 < LL) ? (l + 2) : (LL - 1);
            const float4 bp4 = ((const float4*)(base_e_g + lb * NE))[t];
            bn[0]  = bp4.x; bn[1]  = bp4.y; bn[2]  = bp4.z; bn[3]  = bp4.w;
            const float4 wp4 = ((const float4*)(wde_e_g + lw * NE))[t];
            wn2[0] = wp4.x; wn2[1] = wp4.y; wn2[2] = wp4.z; wn2[3] = wp4.w;
        }

        if (l > 0) {
            const float rr = s_rho[l - 1];
            const int   pb = (l - 1) & 1;
            float acc = 0.0f;
            #pragma unroll
            for (int i = 0; i < 2; ++i) {
                int n = t + i * NT;
                float be = s_bel[pb][n];
                float sp = fmaxf(be, 0.0f) + __logf(1.0f + __expf(-fabsf(be)));
                acc += sp - omeg[i] * be;
                s_bel[pb][n] = bias[i];
            }
            loss += rr * acc;
        }

        {
            const int sb = (l + 2) % 3;
            s_S[sb][t] = 0.0f;
            s_S[sb][t + NT] = 0.0f;
        }

        unsigned long long tB = clock64();

        const float rw_ = s_rw[l];
        const int cs = l % 3, ns = (l + 1) % 3, bb = l & 1;

        float d[HE];
        #pragma unroll
        for (int k = 0; k < HE; ++k) {
            float te = bc[k] + s_S[cs][col[k]] - msg[k];
            float e  = __expf(te);
            float dd = 1.0f - 2.0f * __builtin_amdgcn_rcpf(e + 1.0f);
            dd = fminf(fmaxf(dd, -1.0f), 1.0f);
            if (dd == 0.0f) dd = 1.0f;
            d[k] = dd;
        }
        float p01 = d[0] * d[1], p23 = d[2] * d[3];
        float p4  = p01 * p23;
        float pot = __shfl_xor(p4, 1, 64);
        float ptot = p4 * pot;

        #pragma unroll
        for (int k = 0; k < HE; ++k) {
            float x  = ptot * __builtin_amdgcn_rcpf(d[k]);
            float r  = (1.0f + x) * __builtin_amdgcn_rcpf(1.0f - x);
            float nm = sgn * __logf(r) + rw_ * msg[k];
            msg[k] = nm;
            unsafeAtomicAdd(&s_S[ns][col[k]], nm * wS[k]);
            unsafeAtomicAdd(&s_bel[bb][col[k]], nm * marg[k]);
        }

        #pragma unroll
        for (int k = 0; k < HE; ++k) { bc[k] = bn[k]; wS[k] = wn2[k]; }

        unsigned long long tC = clock64();
        asm volatile("s_waitcnt vmcnt(0) lgkmcnt(0)" ::: "memory");
        unsigned long long tD = clock64();
        __syncthreads();
        unsigned long long tE = clock64();

        p0 += tB - tA; p1 += tC - tB; p2 += tD - tC; p3 += tE - tD;
    }

    {
        const float rr = s_rho[LL - 1];
        const int   pb = (LL - 1) & 1;
        float acc = 0.0f;
        #pragma unroll
        for (int i = 0; i < 2; ++i) {
            int n = t + i * NT;
            float be = s_bel[pb][n];
            float sp = fmaxf(be, 0.0f) + __logf(1.0f + __expf(-fabsf(be)));
            acc += sp - omeg[i] * be;
        }
        loss += rr * acc;
    }

    #pragma unroll
    for (int off = 32; off > 0; off >>= 1)
        loss += __shfl_down(loss, off, 64);
    int wave = t >> 6, lane = t & 63;
    if (lane == 0) s_red[wave] = loss;
    __syncthreads();
    if (t == 0) {
        float tot = 0.0f;
        #pragma unroll
        for (int w = 0; w < 12; ++w) tot += s_red[w];
        atomicAdd(out, tot * (1.0f / (float)MB));
        if (b == 0) { diag[0] = p0; diag[1] = p1; diag[2] = p2; diag[3] = p3; }
    }
}

// ---------------------------------------------------------------------------
extern "C" void kernel_launch(void* const* d_in, const int* in_sizes, int n_in,
                              void* d_out, int out_size, void* d_ws, size_t ws_size,
                              hipStream_t stream) {
    const float* synd     = (const float*)d_in[0];
    const float* errors   = (const float*)d_in[1];
    const float* H        = (const float*)d_in[2];
    const float* llrs     = (const float*)d_in[3];
    const float* w_de     = (const float*)d_in[4];
    const float* w_llr    = (const float*)d_in[5];
    const float* marg_de  = (const float*)d_in[6];
    const float* marg_llr = (const float*)d_in[7];
    const float* res_w    = (const float*)d_in[8];
    const float* rhos     = (const float*)d_in[9];
    float* out = (float*)d_out;

    int*   col_idx = (int*)d_ws;            // NE ints
    float* marg_e  = (float*)d_ws + NE;     // NE floats
    float* base_e  = marg_e + NE;           // L*NE floats
    float* wde_e   = base_e + LL * NE;      // L*NE floats
    unsigned long long* diag =
        (unsigned long long*)((char*)d_ws + ws_size - 128);   // 4 ULL timers
    unsigned long long* sink =
        (unsigned long long*)((char*)d_ws + ws_size - 64);    // reporter sinks

    setup_kernel<<<MM, 256, 0, stream>>>(H, llrs, w_llr, w_de, marg_de,
                                         col_idx, marg_e, base_e, wde_e, out);
    bp_kernel<<<MB, NT, 0, stream>>>(synd, errors, llrs, marg_llr, res_w, rhos,
                                     col_idx, marg_e, base_e, wde_e, out, diag);
    // Diagnostics: dur_us of rep_pi  =  (phase-i cycles over 20 layers) / 2400
    rep_p0<<<1, 64, 0, stream>>>(diag, sink);
    rep_p1<<<1, 64, 0, stream>>>(diag, sink);
    rep_p2<<<1, 64, 0, stream>>>(diag, sink);
    rep_p3<<<1, 64, 0, stream>>>(diag, sink);
}